// Round 9
// baseline (98.462 us; speedup 1.0000x reference)
//
#include <hip/hip_runtime.h>

constexpr int Tn = 512;       // seq len
constexpr int Bn = 4096;      // batch
constexpr int CH = 32;        // timesteps per chunk
constexpr int NCH = Tn / CH;  // 16
constexpr int WPB = 8;        // waves per block -> 2 per SIMD (co-residency)

// Gates are computed PRE-SCALED by folding these into weights/biases:
// i,f,o by -log2e (sigmoid), g by +2*log2e (tanh). Cell state c is carried
// scaled by +2*log2e so exp2(c_s) needs no multiply.
constexpr float NL2E = -1.44269504088896340736f;
constexpr float P2L2E = 2.88539008177792681472f;

#if defined(__has_builtin)
#if __has_builtin(__builtin_amdgcn_exp2f)
#define EXP2F(x) __builtin_amdgcn_exp2f(x)
#else
#define EXP2F(x) exp2f(x)
#endif
#else
#define EXP2F(x) exp2f(x)
#endif

// row_shr:1 within 16-lane rows: dst[i] = src[i-1]; lane0 of row keeps old.
__device__ __forceinline__ float dpp_shr1(float v) {
  return __int_as_float(__builtin_amdgcn_update_dpp(
      __float_as_int(v), __float_as_int(v), 0x111, 0xf, 0xf, false));
}

// One LSTM pipeline tick, shared-denominator form (R7 tick: 5 exp2 + 2 rcp).
//   c' = [c*P + 2l2e*(Eg-1)*Q] * rcp(Q*P)   (scaled cell)
//   h  = (Ec-1) * rcp((1+Eo)*(1+Ec)),  Ec = 2^min(c',80)
template <bool GATED>
__device__ __forceinline__ void tick(float& h, float& c, const float4 pre,
                                     const float4 wih, const float4 whh,
                                     unsigned tau, unsigned lg) {
  const float h_in = dpp_shr1(h);
  const float ag = fmaf(h, whh.z, fmaf(h_in, wih.z, pre.z));  // 2l2e*z_g
  const float ai = fmaf(h, whh.x, fmaf(h_in, wih.x, pre.x));  // -l2e*z_i
  const float af = fmaf(h, whh.y, fmaf(h_in, wih.y, pre.y));  // -l2e*z_f
  const float ao = fmaf(h, whh.w, fmaf(h_in, wih.w, pre.w));  // -l2e*z_o
  const float Eg = EXP2F(ag);  // critical gate first
  const float Ei = EXP2F(ai);
  const float Ef = EXP2F(af);
  const float Eo = EXP2F(ao);
  const float v = 1.0f + Eg;
  const float u = 1.0f + Ei;
  const float Q = 1.0f + Ef;
  const float P = u * v;
  const float QP = Q * P;
  const float R = __builtin_amdgcn_rcpf(QP);
  const float ws = fmaf(P2L2E, Eg, -P2L2E);  // 2l2e*(Eg-1)
  const float num = fmaf(c, P, ws * Q);      // overlaps rcp
  const float cn = num * R;                  // new scaled cell
  const float Ec = EXP2F(fminf(cn, 80.0f));  // clamp keeps products finite
  const float so = 1.0f + Eo;
  const float t2 = 1.0f + Ec;
  const float R2 = __builtin_amdgcn_rcpf(so * t2);
  const float hn = (Ec - 1.0f) * R2;
  if (GATED) {
    const bool act = (tau - lg) < (unsigned)Tn;  // unsigned wrap: tau<lg off
    c = act ? cn : c;
    h = act ? hn : h;
  } else {
    c = cn;
    h = hn;
  }
}

// Fused: layer-0 projection (streaming x) + 6-layer DPP-pipelined recurrence.
// 64 blocks x 8 waves: 2 waves per SIMD on 64 CUs so HW co-scheduling fills
// each wave's dependency-stall slots. Waves independent; per-wave LDS slices.
__global__ __launch_bounds__(WPB * 64, 1) void lstm_fused_kernel(
    const float* __restrict__ x, const float* __restrict__ w_ih0,
    const float* __restrict__ w_ih_rest, const float* __restrict__ w_hh,
    const float* __restrict__ b_ih, const float* __restrict__ b_hh,
    float* __restrict__ out) {
  __shared__ __align__(16) float4 bufA[WPB][CH * 8];  // [wave][t_local*8+elem]
  __shared__ __align__(16) float4 bufB[WPB][CH * 8];

  const int wv = threadIdx.x >> 6;  // wave in block
  const int ln = threadIdx.x & 63;  // lane in wave
  const int bW = blockIdx.x * (WPB * 8) + wv * 8;  // wave's batch base
  // tick-phase roles
  const int ge = ln >> 3;           // batch element (group) 0..7
  const unsigned lg = ln & 7;       // pipeline lane = layer for lg<6
  const bool is0l = (lg == 0);
  // proj-phase roles
  const int ep = ln & 7;            // element
  const int t8p = ln >> 3;          // t sub-index 0..7

  // ---- per-lane recurrence weights (pre-scaled) ----
  const int l = (lg < 6) ? (int)lg : 5;
  float4 whh = make_float4(NL2E * w_hh[l * 4 + 0], NL2E * w_hh[l * 4 + 1],
                           P2L2E * w_hh[l * 4 + 2], NL2E * w_hh[l * 4 + 3]);
  float4 wih = make_float4(0.f, 0.f, 0.f, 0.f);
  float4 bz = make_float4(0.f, 0.f, 0.f, 0.f);  // non-leader gate bias (scaled)
  if (lg >= 1 && lg < 6) {
    wih = make_float4(NL2E * w_ih_rest[(l - 1) * 4 + 0],
                      NL2E * w_ih_rest[(l - 1) * 4 + 1],
                      P2L2E * w_ih_rest[(l - 1) * 4 + 2],
                      NL2E * w_ih_rest[(l - 1) * 4 + 3]);
    bz = make_float4(NL2E * (b_ih[lg * 4 + 0] + b_hh[lg * 4 + 0]),
                     NL2E * (b_ih[lg * 4 + 1] + b_hh[lg * 4 + 1]),
                     P2L2E * (b_ih[lg * 4 + 2] + b_hh[lg * 4 + 2]),
                     NL2E * (b_ih[lg * 4 + 3] + b_hh[lg * 4 + 3]));
  }
  if (lg >= 6) whh = make_float4(0.f, 0.f, 0.f, 0.f);  // inert lanes
  const float selm = is0l ? 1.0f : 0.0f;  // fma-mask: pre = proj*selm + bz

  // ---- layer-0 projection weights (uniform -> scalar regs), pre-scaled ----
  float w[4][16], pb[4];
  {
    const float sc[4] = {NL2E, NL2E, P2L2E, NL2E};
#pragma unroll
    for (int g = 0; g < 4; ++g) {
      pb[g] = sc[g] * (b_ih[g] + b_hh[g]);
#pragma unroll
      for (int d = 0; d < 16; ++d) w[g][d] = sc[g] * w_ih0[g * 16 + d];
    }
  }

  const float4* x4 = (const float4*)x;
  float4 xs[16];
  float h = 0.f, c = 0.f;
  float4 pA[8], pB[8];

  // lane reads 64 B of x for (bW+ep, t = ci*CH + t8p + 8k), k=0..3
  auto LOADC = [&](int ci) {
    const size_t base = ((size_t)(bW + ep) * Tn + (size_t)ci * CH + t8p) * 4;
#pragma unroll
    for (int k = 0; k < 4; ++k)
#pragma unroll
      for (int i = 0; i < 4; ++i) xs[k * 4 + i] = x4[base + (size_t)k * 32 + i];
  };
  // projection quarter k: t = t8p + 8k of the chunk in xs -> tick block jb=k
  auto PROJq = [&](float4* dst, int k) {
    float s0 = pb[0], s1 = pb[1], s2 = pb[2], s3 = pb[3];
#pragma unroll
    for (int i = 0; i < 4; ++i) {
      const float4 a = xs[k * 4 + i];
      s0 = fmaf(a.x, w[0][i * 4 + 0], s0); s0 = fmaf(a.y, w[0][i * 4 + 1], s0);
      s0 = fmaf(a.z, w[0][i * 4 + 2], s0); s0 = fmaf(a.w, w[0][i * 4 + 3], s0);
      s1 = fmaf(a.x, w[1][i * 4 + 0], s1); s1 = fmaf(a.y, w[1][i * 4 + 1], s1);
      s1 = fmaf(a.z, w[1][i * 4 + 2], s1); s1 = fmaf(a.w, w[1][i * 4 + 3], s1);
      s2 = fmaf(a.x, w[2][i * 4 + 0], s2); s2 = fmaf(a.y, w[2][i * 4 + 1], s2);
      s2 = fmaf(a.z, w[2][i * 4 + 2], s2); s2 = fmaf(a.w, w[2][i * 4 + 3], s2);
      s3 = fmaf(a.x, w[3][i * 4 + 0], s3); s3 = fmaf(a.y, w[3][i * 4 + 1], s3);
      s3 = fmaf(a.z, w[3][i * 4 + 2], s3); s3 = fmaf(a.w, w[3][i * 4 + 3], s3);
    }
    dst[ln + 64 * k] = make_float4(s0, s1, s2, s3);  // [(t8p+8k)*8 + ep]
  };
  // bulk LDS->reg for one 8-tick block (8 broadcast ds_read_b128)
  auto RD = [&](float4* p, const float4* bufc, int jb) {
#pragma unroll
    for (int k = 0; k < 8; ++k) p[k] = bufc[(jb * 8 + k) * 8 + ge];
  };
  // 8 clean ticks consuming p (mask applied off critical path)
  auto T = [&](float4* p) {
    float4 q[8];
#pragma unroll
    for (int k = 0; k < 8; ++k) {
      q[k].x = fmaf(p[k].x, selm, bz.x);
      q[k].y = fmaf(p[k].y, selm, bz.y);
      q[k].z = fmaf(p[k].z, selm, bz.z);
      q[k].w = fmaf(p[k].w, selm, bz.w);
    }
#pragma unroll
    for (int k = 0; k < 8; ++k) tick<false>(h, c, q[k], wih, whh, 0u, 0u);
  };
  auto Tg = [&](float4* p, unsigned tau0) {
    float4 q[8];
#pragma unroll
    for (int k = 0; k < 8; ++k) {
      q[k].x = fmaf(p[k].x, selm, bz.x);
      q[k].y = fmaf(p[k].y, selm, bz.y);
      q[k].z = fmaf(p[k].z, selm, bz.z);
      q[k].w = fmaf(p[k].w, selm, bz.w);
    }
#pragma unroll
    for (int k = 0; k < 8; ++k)
      tick<true>(h, c, q[k], wih, whh, tau0 + (unsigned)k, lg);
  };

  float4* bA = bufA[wv];
  float4* bB = bufB[wv];

  // ---- prologue: chunk 0 -> bufA; chunk 1 x in regs; block0 in pA ----
  LOADC(0);
#pragma unroll
  for (int k = 0; k < 4; ++k) PROJq(bA, k);
  LOADC(1);
  RD(pA, bA, 0);

  // ---- chunk 0 (block 0 gated for pipeline fill), 1 PROJ quarter/block ----
  RD(pB, bA, 1);  Tg(pA, 0u);  PROJq(bB, 0);
  RD(pA, bA, 2);  T(pB);       PROJq(bB, 1);
  RD(pB, bA, 3);  T(pA);       PROJq(bB, 2);
  RD(pA, bB, 0);  T(pB);       PROJq(bB, 3);
  LOADC(2);

  // ---- chunks 1..15 (entry invariant: pA holds block 0 of chunk j) ----
#pragma unroll 1
  for (int j = 1; j < NCH; ++j) {
    const float4* bc = (j & 1) ? bB : bA;
    float4* bn = (j & 1) ? bA : bB;
    const bool more = (j < NCH - 1);
    RD(pB, bc, 1);  T(pA);  if (more) PROJq(bn, 0);
    RD(pA, bc, 2);  T(pB);  if (more) PROJq(bn, 1);
    RD(pB, bc, 3);  T(pA);  if (more) PROJq(bn, 2);
    RD(pA, more ? bn : bc, 0);  T(pB);  if (more) PROJq(bn, 3);
    if (j < NCH - 2) LOADC(j + 2);
  }

  // ---- tail: 5 gated ticks (tau=512..516); leaders inactive, pre=bz ----
#pragma unroll
  for (unsigned k = 0; k < 5; ++k)
    tick<true>(h, c, bz, wih, whh, 512u + k, lg);

  if (lg == 5) out[bW + ge] = h;  // H=1: hidden channel 0 == h
}

extern "C" void kernel_launch(void* const* d_in, const int* in_sizes, int n_in,
                              void* d_out, int out_size, void* d_ws, size_t ws_size,
                              hipStream_t stream) {
  (void)in_sizes; (void)n_in; (void)out_size; (void)d_ws; (void)ws_size;
  const float* x         = (const float*)d_in[0];
  const float* w_ih0     = (const float*)d_in[1];
  const float* w_ih_rest = (const float*)d_in[2];
  const float* w_hh      = (const float*)d_in[3];
  const float* b_ih      = (const float*)d_in[4];
  const float* b_hh      = (const float*)d_in[5];
  float* out = (float*)d_out;

  lstm_fused_kernel<<<Bn / (WPB * 8), WPB * 64, 0, stream>>>(
      x, w_ih0, w_ih_rest, w_hh, b_ih, b_hh, out);
}

// Round 10
// 58.754 us; speedup vs baseline: 1.6758x; 1.6758x over previous
//
#include <hip/hip_runtime.h>

constexpr int Tn = 512;       // seq len
constexpr int Bn = 4096;      // batch
constexpr int CH = 32;        // timesteps per chunk
constexpr int NCH = Tn / CH;  // 16

// Gates are computed PRE-SCALED by folding these into weights/biases:
// i,f,o by -log2e (sigmoid), g by +2*log2e (tanh). Cell state c is carried
// scaled by +2*log2e so exp2(c_s) needs no multiply.
constexpr float NL2E = -1.44269504088896340736f;
constexpr float P2L2E = 2.88539008177792681472f;

#if defined(__has_builtin)
#if __has_builtin(__builtin_amdgcn_exp2f)
#define EXP2F(x) __builtin_amdgcn_exp2f(x)
#else
#define EXP2F(x) exp2f(x)
#endif
#else
#define EXP2F(x) exp2f(x)
#endif

// row_shr:1 within 16-lane rows: dst[i] = src[i-1]; lane0 of row keeps old.
__device__ __forceinline__ float dpp_shr1(float v) {
  return __int_as_float(__builtin_amdgcn_update_dpp(
      __float_as_int(v), __float_as_int(v), 0x111, 0xf, 0xf, false));
}

// One LSTM pipeline tick, shared-denominator form: 5 exp2 + 3 rcp,
// with the dependency chain minimized:
//   - inner gate fma depends only on h -> runs parallel with dpp_shr1(h)
//   - c' = [c*P + 2l2e*(Eg-1)*Q] * rcp(Q*P)          (scaled cell)
//   - h  = rcp(1+Eo) * (1 - 2*rcp(1+2^c'))           (Inf-safe, no clamp;
//     Ec=Inf -> rcp->0 -> h -> sig_o, the exact mathematical limit)
template <bool GATED>
__device__ __forceinline__ void tick(float& h, float& c, const float4 pre,
                                     const float4 wih, const float4 whh,
                                     unsigned tau, unsigned lg) {
  const float h_in = dpp_shr1(h);            // || with the t* fmas below
  const float tg = fmaf(h, whh.z, pre.z);    // depend only on h
  const float ti = fmaf(h, whh.x, pre.x);
  const float tf = fmaf(h, whh.y, pre.y);
  const float to = fmaf(h, whh.w, pre.w);
  const float ag = fmaf(h_in, wih.z, tg);    // 2l2e*z_g (critical gate)
  const float ai = fmaf(h_in, wih.x, ti);    // -l2e*z_i
  const float af = fmaf(h_in, wih.y, tf);    // -l2e*z_f
  const float ao = fmaf(h_in, wih.w, to);    // -l2e*z_o
  const float Eg = EXP2F(ag);                // critical gate first
  const float Ei = EXP2F(ai);
  const float Ef = EXP2F(af);
  const float Eo = EXP2F(ao);
  const float v = 1.0f + Eg;
  const float u = 1.0f + Ei;
  const float Q = 1.0f + Ef;
  const float P = u * v;
  const float QP = Q * P;
  const float R = __builtin_amdgcn_rcpf(QP);             // on-chain
  const float sig_o = __builtin_amdgcn_rcpf(1.0f + Eo);  // off-chain
  const float ws = fmaf(P2L2E, Eg, -P2L2E);              // 2l2e*(Eg-1)
  const float num = fmaf(c, P, ws * Q);                  // overlaps rcp
  const float cn = num * R;                              // new scaled cell
  const float Ec = EXP2F(cn);                            // Inf ok
  const float rt = __builtin_amdgcn_rcpf(1.0f + Ec);     // on-chain
  const float th = fmaf(-2.0f, rt, 1.0f);                // tanh(c)
  const float hn = sig_o * th;
  if (GATED) {
    const bool act = (tau - lg) < (unsigned)Tn;  // unsigned wrap: tau<lg off
    c = act ? cn : c;
    h = act ? hn : h;
  } else {
    c = cn;
    h = hn;
  }
}

// Fused: layer-0 projection (streaming x) + 6-layer DPP-pipelined recurrence.
// 512 single-wave blocks (2 blocks/CU). Projection tiles double-buffered in
// LDS; register prefetch (pA/pB) per 8-tick block. PROJ placement = R7.
__global__ __launch_bounds__(64, 1) void lstm_fused_kernel(
    const float* __restrict__ x, const float* __restrict__ w_ih0,
    const float* __restrict__ w_ih_rest, const float* __restrict__ w_hh,
    const float* __restrict__ b_ih, const float* __restrict__ b_hh,
    float* __restrict__ out) {
  __shared__ __align__(16) float4 bufA[CH * 8];  // [t_local][elem]
  __shared__ __align__(16) float4 bufB[CH * 8];

  const int ln = threadIdx.x;
  const int bW = blockIdx.x * 8;  // wave's batch base
  // tick-phase roles
  const int ge = ln >> 3;         // batch element (group) 0..7
  const unsigned lg = ln & 7;     // pipeline lane = layer for lg<6
  const bool is0l = (lg == 0);
  // proj-phase roles
  const int ep = ln & 7;          // element
  const int t8p = ln >> 3;        // t sub-index 0..7

  // ---- per-lane recurrence weights (pre-scaled) ----
  const int l = (lg < 6) ? (int)lg : 5;
  float4 whh = make_float4(NL2E * w_hh[l * 4 + 0], NL2E * w_hh[l * 4 + 1],
                           P2L2E * w_hh[l * 4 + 2], NL2E * w_hh[l * 4 + 3]);
  float4 wih = make_float4(0.f, 0.f, 0.f, 0.f);
  float4 bz = make_float4(0.f, 0.f, 0.f, 0.f);  // non-leader gate bias (scaled)
  if (lg >= 1 && lg < 6) {
    wih = make_float4(NL2E * w_ih_rest[(l - 1) * 4 + 0],
                      NL2E * w_ih_rest[(l - 1) * 4 + 1],
                      P2L2E * w_ih_rest[(l - 1) * 4 + 2],
                      NL2E * w_ih_rest[(l - 1) * 4 + 3]);
    bz = make_float4(NL2E * (b_ih[lg * 4 + 0] + b_hh[lg * 4 + 0]),
                     NL2E * (b_ih[lg * 4 + 1] + b_hh[lg * 4 + 1]),
                     P2L2E * (b_ih[lg * 4 + 2] + b_hh[lg * 4 + 2]),
                     NL2E * (b_ih[lg * 4 + 3] + b_hh[lg * 4 + 3]));
  }
  if (lg >= 6) whh = make_float4(0.f, 0.f, 0.f, 0.f);  // inert lanes
  const float selm = is0l ? 1.0f : 0.0f;  // fma-mask: pre = proj*selm + bz

  // ---- layer-0 projection weights (uniform -> scalar regs), pre-scaled ----
  float w[4][16], pb[4];
  {
    const float sc[4] = {NL2E, NL2E, P2L2E, NL2E};
#pragma unroll
    for (int g = 0; g < 4; ++g) {
      pb[g] = sc[g] * (b_ih[g] + b_hh[g]);
#pragma unroll
      for (int d = 0; d < 16; ++d) w[g][d] = sc[g] * w_ih0[g * 16 + d];
    }
  }

  const float4* x4 = (const float4*)x;
  float4 xs[16];
  float h = 0.f, c = 0.f;
  float4 pA[8], pB[8];

  // lane reads 64 B of x for (bW+ep, t = ci*CH + t8p + 8k), k=0..3
  auto LOADC = [&](int ci) {
    const size_t base = ((size_t)(bW + ep) * Tn + (size_t)ci * CH + t8p) * 4;
#pragma unroll
    for (int k = 0; k < 4; ++k)
#pragma unroll
      for (int i = 0; i < 4; ++i) xs[k * 4 + i] = x4[base + (size_t)k * 32 + i];
  };
  // projection quarter k: t = t8p + 8k of the chunk in xs -> tick block jb=k
  auto PROJq = [&](float4* dst, int k) {
    float s0 = pb[0], s1 = pb[1], s2 = pb[2], s3 = pb[3];
#pragma unroll
    for (int i = 0; i < 4; ++i) {
      const float4 a = xs[k * 4 + i];
      s0 = fmaf(a.x, w[0][i * 4 + 0], s0); s0 = fmaf(a.y, w[0][i * 4 + 1], s0);
      s0 = fmaf(a.z, w[0][i * 4 + 2], s0); s0 = fmaf(a.w, w[0][i * 4 + 3], s0);
      s1 = fmaf(a.x, w[1][i * 4 + 0], s1); s1 = fmaf(a.y, w[1][i * 4 + 1], s1);
      s1 = fmaf(a.z, w[1][i * 4 + 2], s1); s1 = fmaf(a.w, w[1][i * 4 + 3], s1);
      s2 = fmaf(a.x, w[2][i * 4 + 0], s2); s2 = fmaf(a.y, w[2][i * 4 + 1], s2);
      s2 = fmaf(a.z, w[2][i * 4 + 2], s2); s2 = fmaf(a.w, w[2][i * 4 + 3], s2);
      s3 = fmaf(a.x, w[3][i * 4 + 0], s3); s3 = fmaf(a.y, w[3][i * 4 + 1], s3);
      s3 = fmaf(a.z, w[3][i * 4 + 2], s3); s3 = fmaf(a.w, w[3][i * 4 + 3], s3);
    }
    dst[ln + 64 * k] = make_float4(s0, s1, s2, s3);  // [(t8p+8k)*8 + ep]
  };
  // bulk LDS->reg for one 8-tick block (8 broadcast ds_read_b128)
  auto RD = [&](float4* p, const float4* bufc, int jb) {
#pragma unroll
    for (int k = 0; k < 8; ++k) p[k] = bufc[(jb * 8 + k) * 8 + ge];
  };
  // 8 clean ticks consuming p (mask applied off critical path)
  auto T = [&](float4* p) {
    float4 q[8];
#pragma unroll
    for (int k = 0; k < 8; ++k) {
      q[k].x = fmaf(p[k].x, selm, bz.x);
      q[k].y = fmaf(p[k].y, selm, bz.y);
      q[k].z = fmaf(p[k].z, selm, bz.z);
      q[k].w = fmaf(p[k].w, selm, bz.w);
    }
#pragma unroll
    for (int k = 0; k < 8; ++k) tick<false>(h, c, q[k], wih, whh, 0u, 0u);
  };
  auto Tg = [&](float4* p, unsigned tau0) {
    float4 q[8];
#pragma unroll
    for (int k = 0; k < 8; ++k) {
      q[k].x = fmaf(p[k].x, selm, bz.x);
      q[k].y = fmaf(p[k].y, selm, bz.y);
      q[k].z = fmaf(p[k].z, selm, bz.z);
      q[k].w = fmaf(p[k].w, selm, bz.w);
    }
#pragma unroll
    for (int k = 0; k < 8; ++k)
      tick<true>(h, c, q[k], wih, whh, tau0 + (unsigned)k, lg);
  };

  // ---- prologue: chunk 0 -> bufA; chunk 1 x in regs; block0 in pA ----
  LOADC(0);
#pragma unroll
  for (int k = 0; k < 4; ++k) PROJq(bufA, k);
  LOADC(1);
  RD(pA, bufA, 0);

  // ---- chunk 0 (block 0 gated for pipeline fill) ----
  RD(pB, bufA, 1);  Tg(pA, 0u);
  RD(pA, bufA, 2);  T(pB);
  PROJq(bufB, 0);  PROJq(bufB, 1);
  RD(pB, bufA, 3);  T(pA);
  PROJq(bufB, 2);  PROJq(bufB, 3);
  RD(pA, bufB, 0);  T(pB);
  LOADC(2);

  // ---- chunks 1..15 (entry invariant: pA holds block 0 of chunk j) ----
#pragma unroll 1
  for (int j = 1; j < NCH; ++j) {
    const float4* bc = (j & 1) ? bufB : bufA;
    float4* bn = (j & 1) ? bufA : bufB;
    RD(pB, bc, 1);  T(pA);
    RD(pA, bc, 2);  T(pB);
    if (j < NCH - 1) { PROJq(bn, 0); PROJq(bn, 1); }
    RD(pB, bc, 3);  T(pA);
    if (j < NCH - 1) { PROJq(bn, 2); PROJq(bn, 3); }
    RD(pA, (j < NCH - 1) ? bn : bc, 0);  T(pB);
    if (j < NCH - 2) LOADC(j + 2);
  }

  // ---- tail: 5 gated ticks (tau=512..516); leaders inactive, pre=bz ----
#pragma unroll
  for (unsigned k = 0; k < 5; ++k)
    tick<true>(h, c, bz, wih, whh, 512u + k, lg);

  if (lg == 5) out[bW + ge] = h;  // H=1: hidden channel 0 == h
}

extern "C" void kernel_launch(void* const* d_in, const int* in_sizes, int n_in,
                              void* d_out, int out_size, void* d_ws, size_t ws_size,
                              hipStream_t stream) {
  (void)in_sizes; (void)n_in; (void)out_size; (void)d_ws; (void)ws_size;
  const float* x         = (const float*)d_in[0];
  const float* w_ih0     = (const float*)d_in[1];
  const float* w_ih_rest = (const float*)d_in[2];
  const float* w_hh      = (const float*)d_in[3];
  const float* b_ih      = (const float*)d_in[4];
  const float* b_hh      = (const float*)d_in[5];
  float* out = (float*)d_out;

  lstm_fused_kernel<<<Bn / 8, 64, 0, stream>>>(x, w_ih0, w_ih_rest, w_hh,
                                               b_ih, b_hh, out);
}

// Round 11
// 54.697 us; speedup vs baseline: 1.8001x; 1.0742x over previous
//
#include <hip/hip_runtime.h>

constexpr int Tn = 512;       // seq len
constexpr int Bn = 4096;      // batch
constexpr int CH = 32;        // timesteps per chunk
constexpr int NCH = Tn / CH;  // 16

// Gates are computed PRE-SCALED by folding these into weights/biases:
// i,f,o by -log2e (sigmoid), g by +2*log2e (tanh). Cell state c is carried
// scaled by +2*log2e so exp2(c_s) needs no multiply.
constexpr float NL2E = -1.44269504088896340736f;
constexpr float P2L2E = 2.88539008177792681472f;

#if defined(__has_builtin)
#if __has_builtin(__builtin_amdgcn_exp2f)
#define EXP2F(x) __builtin_amdgcn_exp2f(x)
#else
#define EXP2F(x) exp2f(x)
#endif
#else
#define EXP2F(x) exp2f(x)
#endif

// row_shr:1 within 16-lane rows: dst[i] = src[i-1]; lane0 of row keeps old.
__device__ __forceinline__ float dpp_shr1(float v) {
  return __int_as_float(__builtin_amdgcn_update_dpp(
      __float_as_int(v), __float_as_int(v), 0x111, 0xf, 0xf, false));
}

// One LSTM pipeline tick (R10 tick, unchanged): 5 exp2 + 3 rcp.
//   - inner gate fma depends only on h -> runs parallel with dpp_shr1(h)
//   - c' = [c*P + 2l2e*(Eg-1)*Q] * rcp(Q*P)          (scaled cell)
//   - h  = rcp(1+Eo) * (1 - 2*rcp(1+2^c'))           (Inf-safe, no clamp)
template <bool GATED>
__device__ __forceinline__ void tick(float& h, float& c, const float4 pre,
                                     const float4 wih, const float4 whh,
                                     unsigned tau, unsigned lg) {
  const float h_in = dpp_shr1(h);            // || with the t* fmas below
  const float tg = fmaf(h, whh.z, pre.z);    // depend only on h
  const float ti = fmaf(h, whh.x, pre.x);
  const float tf = fmaf(h, whh.y, pre.y);
  const float to = fmaf(h, whh.w, pre.w);
  const float ag = fmaf(h_in, wih.z, tg);    // 2l2e*z_g (critical gate)
  const float ai = fmaf(h_in, wih.x, ti);    // -l2e*z_i
  const float af = fmaf(h_in, wih.y, tf);    // -l2e*z_f
  const float ao = fmaf(h_in, wih.w, to);    // -l2e*z_o
  const float Eg = EXP2F(ag);                // critical gate first
  const float Ei = EXP2F(ai);
  const float Ef = EXP2F(af);
  const float Eo = EXP2F(ao);
  const float v = 1.0f + Eg;
  const float u = 1.0f + Ei;
  const float Q = 1.0f + Ef;
  const float P = u * v;
  const float QP = Q * P;
  const float R = __builtin_amdgcn_rcpf(QP);             // on-chain
  const float sig_o = __builtin_amdgcn_rcpf(1.0f + Eo);  // off-chain
  const float ws = fmaf(P2L2E, Eg, -P2L2E);              // 2l2e*(Eg-1)
  const float num = fmaf(c, P, ws * Q);                  // overlaps rcp
  const float cn = num * R;                              // new scaled cell
  const float Ec = EXP2F(cn);                            // Inf ok
  const float rt = __builtin_amdgcn_rcpf(1.0f + Ec);     // on-chain
  const float th = fmaf(-2.0f, rt, 1.0f);                // tanh(c)
  const float hn = sig_o * th;
  if (GATED) {
    const bool act = (tau - lg) < (unsigned)Tn;  // unsigned wrap: tau<lg off
    c = act ? cn : c;
    h = act ? hn : h;
  } else {
    c = cn;
    h = hn;
  }
}

// Fused: layer-0 projection (streaming x) + 6-layer DPP-pipelined recurrence.
// 512 single-wave blocks. Pre-masked LDS addressing: leaders read the
// projection tile, non-leaders read a replicated bias region at the SAME
// immediate offsets -> RD output is the final gate base, no per-tick mask fma.
__global__ __launch_bounds__(64, 1) void lstm_fused_kernel(
    const float* __restrict__ x, const float* __restrict__ w_ih0,
    const float* __restrict__ w_ih_rest, const float* __restrict__ w_hh,
    const float* __restrict__ b_ih, const float* __restrict__ b_hh,
    float* __restrict__ out) {
  __shared__ __align__(16) float4 bufA[CH * 8];    // [t_local][elem]
  __shared__ __align__(16) float4 bufB[CH * 8];
  __shared__ __align__(16) float4 biasRep[32 * 8]; // [row][lg] = bz(lg)

  const int ln = threadIdx.x;
  const int bW = blockIdx.x * 8;  // wave's batch base
  // tick-phase roles
  const int ge = ln >> 3;         // batch element (group) 0..7
  const unsigned lg = ln & 7;     // pipeline lane = layer for lg<6
  const bool is0l = (lg == 0);
  // proj-phase roles
  const int ep = ln & 7;          // element
  const int t8p = ln >> 3;        // t sub-index 0..7

  // ---- per-lane recurrence weights (pre-scaled) ----
  const int l = (lg < 6) ? (int)lg : 5;
  float4 whh = make_float4(NL2E * w_hh[l * 4 + 0], NL2E * w_hh[l * 4 + 1],
                           P2L2E * w_hh[l * 4 + 2], NL2E * w_hh[l * 4 + 3]);
  float4 wih = make_float4(0.f, 0.f, 0.f, 0.f);
  float4 bz = make_float4(0.f, 0.f, 0.f, 0.f);  // non-leader gate bias (scaled)
  if (lg >= 1 && lg < 6) {
    wih = make_float4(NL2E * w_ih_rest[(l - 1) * 4 + 0],
                      NL2E * w_ih_rest[(l - 1) * 4 + 1],
                      P2L2E * w_ih_rest[(l - 1) * 4 + 2],
                      NL2E * w_ih_rest[(l - 1) * 4 + 3]);
    bz = make_float4(NL2E * (b_ih[lg * 4 + 0] + b_hh[lg * 4 + 0]),
                     NL2E * (b_ih[lg * 4 + 1] + b_hh[lg * 4 + 1]),
                     P2L2E * (b_ih[lg * 4 + 2] + b_hh[lg * 4 + 2]),
                     NL2E * (b_ih[lg * 4 + 3] + b_hh[lg * 4 + 3]));
  }
  if (lg >= 6) whh = make_float4(0.f, 0.f, 0.f, 0.f);  // inert lanes

  // ---- fill the replicated bias region: row r, slot lg -> bz(lg) ----
  // lane ln writes rows rep*8 + t8p at slot ep with its own bz (lg == ep).
#pragma unroll
  for (int rep = 0; rep < 4; ++rep) biasRep[rep * 64 + ln] = bz;

  // per-lane read bases: leader walks the projection tile, others the bias
  // region; both consumed with the same immediate offsets (jb*8+k)*128.
  const char* rbA = is0l ? (const char*)(bufA + ge) : (const char*)(biasRep + (int)lg);
  const char* rbB = is0l ? (const char*)(bufB + ge) : (const char*)(biasRep + (int)lg);

  // ---- layer-0 projection weights (uniform -> scalar regs), pre-scaled ----
  float w[4][16], pb[4];
  {
    const float sc[4] = {NL2E, NL2E, P2L2E, NL2E};
#pragma unroll
    for (int g = 0; g < 4; ++g) {
      pb[g] = sc[g] * (b_ih[g] + b_hh[g]);
#pragma unroll
      for (int d = 0; d < 16; ++d) w[g][d] = sc[g] * w_ih0[g * 16 + d];
    }
  }

  const float4* x4 = (const float4*)x;
  float4 xs[16];
  float h = 0.f, c = 0.f;
  float4 pA[8], pB[8];

  // lane reads 64 B of x for (bW+ep, t = ci*CH + t8p + 8k), k=0..3
  auto LOADC = [&](int ci) {
    const size_t base = ((size_t)(bW + ep) * Tn + (size_t)ci * CH + t8p) * 4;
#pragma unroll
    for (int k = 0; k < 4; ++k)
#pragma unroll
      for (int i = 0; i < 4; ++i) xs[k * 4 + i] = x4[base + (size_t)k * 32 + i];
  };
  // projection quarter k: t = t8p + 8k of the chunk in xs -> tick block jb=k
  auto PROJq = [&](float4* dst, int k) {
    float s0 = pb[0], s1 = pb[1], s2 = pb[2], s3 = pb[3];
#pragma unroll
    for (int i = 0; i < 4; ++i) {
      const float4 a = xs[k * 4 + i];
      s0 = fmaf(a.x, w[0][i * 4 + 0], s0); s0 = fmaf(a.y, w[0][i * 4 + 1], s0);
      s0 = fmaf(a.z, w[0][i * 4 + 2], s0); s0 = fmaf(a.w, w[0][i * 4 + 3], s0);
      s1 = fmaf(a.x, w[1][i * 4 + 0], s1); s1 = fmaf(a.y, w[1][i * 4 + 1], s1);
      s1 = fmaf(a.z, w[1][i * 4 + 2], s1); s1 = fmaf(a.w, w[1][i * 4 + 3], s1);
      s2 = fmaf(a.x, w[2][i * 4 + 0], s2); s2 = fmaf(a.y, w[2][i * 4 + 1], s2);
      s2 = fmaf(a.z, w[2][i * 4 + 2], s2); s2 = fmaf(a.w, w[2][i * 4 + 3], s2);
      s3 = fmaf(a.x, w[3][i * 4 + 0], s3); s3 = fmaf(a.y, w[3][i * 4 + 1], s3);
      s3 = fmaf(a.z, w[3][i * 4 + 2], s3); s3 = fmaf(a.w, w[3][i * 4 + 3], s3);
    }
    dst[ln + 64 * k] = make_float4(s0, s1, s2, s3);  // [(t8p+8k)*8 + ep]
  };
  // bulk LDS->reg for one 8-tick block: 8 ds_read_b128, per-lane base +
  // uniform immediate offsets; result IS the gate base (pre-masked).
  auto RD = [&](float4* p, const char* b, int jb) {
#pragma unroll
    for (int k = 0; k < 8; ++k)
      p[k] = *(const float4*)(b + (size_t)((jb * 8 + k) * 128));
  };
  // 8 clean ticks consuming p directly
  auto T = [&](float4* p) {
#pragma unroll
    for (int k = 0; k < 8; ++k) tick<false>(h, c, p[k], wih, whh, 0u, 0u);
  };
  auto Tg = [&](float4* p, unsigned tau0) {
#pragma unroll
    for (int k = 0; k < 8; ++k)
      tick<true>(h, c, p[k], wih, whh, tau0 + (unsigned)k, lg);
  };

  // ---- prologue: chunk 0 -> bufA; chunk 1 x in regs; block0 in pA ----
  LOADC(0);
#pragma unroll
  for (int k = 0; k < 4; ++k) PROJq(bufA, k);
  LOADC(1);
  RD(pA, rbA, 0);

  // ---- chunk 0 (block 0 gated for pipeline fill) ----
  RD(pB, rbA, 1);  Tg(pA, 0u);
  RD(pA, rbA, 2);  T(pB);
  PROJq(bufB, 0);  PROJq(bufB, 1);
  RD(pB, rbA, 3);  T(pA);
  PROJq(bufB, 2);  PROJq(bufB, 3);
  RD(pA, rbB, 0);  T(pB);
  LOADC(2);

  // ---- chunks 1..15 (entry invariant: pA holds block 0 of chunk j) ----
#pragma unroll 1
  for (int j = 1; j < NCH; ++j) {
    const char* rc = (j & 1) ? rbB : rbA;
    const char* rn = (j & 1) ? rbA : rbB;
    float4* bn = (j & 1) ? bufA : bufB;
    RD(pB, rc, 1);  T(pA);
    RD(pA, rc, 2);  T(pB);
    if (j < NCH - 1) { PROJq(bn, 0); PROJq(bn, 1); }
    RD(pB, rc, 3);  T(pA);
    if (j < NCH - 1) { PROJq(bn, 2); PROJq(bn, 3); }
    RD(pA, (j < NCH - 1) ? rn : rc, 0);  T(pB);
    if (j < NCH - 2) LOADC(j + 2);
  }

  // ---- tail: 5 gated ticks (tau=512..516); leaders inactive, pre=bz ----
#pragma unroll
  for (unsigned k = 0; k < 5; ++k)
    tick<true>(h, c, bz, wih, whh, 512u + k, lg);

  if (lg == 5) out[bW + ge] = h;  // H=1: hidden channel 0 == h
}

extern "C" void kernel_launch(void* const* d_in, const int* in_sizes, int n_in,
                              void* d_out, int out_size, void* d_ws, size_t ws_size,
                              hipStream_t stream) {
  (void)in_sizes; (void)n_in; (void)out_size; (void)d_ws; (void)ws_size;
  const float* x         = (const float*)d_in[0];
  const float* w_ih0     = (const float*)d_in[1];
  const float* w_ih_rest = (const float*)d_in[2];
  const float* w_hh      = (const float*)d_in[3];
  const float* b_ih      = (const float*)d_in[4];
  const float* b_hh      = (const float*)d_in[5];
  float* out = (float*)d_out;

  lstm_fused_kernel<<<Bn / 8, 64, 0, stream>>>(x, w_ih0, w_ih_rest, w_hh,
                                               b_ih, b_hh, out);
}